// Round 2
// baseline (890.856 us; speedup 1.0000x reference)
//
#include <hip/hip_runtime.h>

#define LL 200      // history length
#define DD 128      // attention dim
#define NH 4        // heads
#define WPB 4       // waves per block = batch rows per block
#define RSCALE 0.17677669529663687f   // 1/sqrt(32)

__device__ __forceinline__ float blo(unsigned int u) { return __uint_as_float(u << 16); }
__device__ __forceinline__ float bhi(unsigned int u) { return __uint_as_float(u & 0xffff0000u); }
__device__ __forceinline__ float b2f(unsigned short u) { return __uint_as_float(((unsigned int)u) << 16); }
__device__ __forceinline__ unsigned short f2bf(float f) {
  unsigned int u = __float_as_uint(f);
  u += 0x7fffu + ((u >> 16) & 1u);   // RNE
  return (unsigned short)(u >> 16);
}
__device__ __forceinline__ unsigned int pack2(float lo, float hi) {
  return ((unsigned int)f2bf(hi) << 16) | (unsigned int)f2bf(lo);
}

// dot of a 128-wide weight row (bf16 or f32, global) with a 128-float LDS vector
template <bool F32>
__device__ __forceinline__ float rowdot128(const void* __restrict__ wrow,
                                           const float* __restrict__ v) {
  float acc = 0.f;
  if constexpr (F32) {
    const float4* wr = (const float4*)wrow;
#pragma unroll
    for (int k = 0; k < 32; k++) {
      float4 w = wr[k];
      float4 vv = *(const float4*)(v + 4 * k);
      acc += w.x * vv.x + w.y * vv.y + w.z * vv.z + w.w * vv.w;
    }
  } else {
    const uint4* wr = (const uint4*)wrow;
#pragma unroll
    for (int k = 0; k < 16; k++) {
      uint4 u = wr[k];
      float4 v0 = *(const float4*)(v + k * 8);
      float4 v1 = *(const float4*)(v + k * 8 + 4);
      acc += blo(u.x) * v0.x + bhi(u.x) * v0.y + blo(u.y) * v0.z + bhi(u.y) * v0.w;
      acc += blo(u.z) * v1.x + bhi(u.z) * v1.y + blo(u.w) * v1.z + bhi(u.w) * v1.w;
    }
  }
  return acc;
}

template <bool F32>
__device__ __forceinline__ float welem(const void* w, size_t idx) {
  if constexpr (F32) return ((const float*)w)[idx];
  else               return b2f(((const unsigned short*)w)[idx]);
}

// Per-wave LDS slice: 6272 B. Block = 4 slices = 25 KB -> 5 blocks/CU.
struct __align__(16) WaveSmem {
  float qt[NH * DD];   // 2048B: q~ laid out [j][h]; reused as cvec[4][128] after phase B
  float sc[LL * NH];   // 3200B: compacted attn [pos][h]
  float u[2 * DD];     // 1024B: tvec[0:128]+qv[128:256] -> sidx[200] (ints) -> ovec[0:128]
};

template <bool F32>
__device__ __forceinline__ void body(WaveSmem& ws, const int lane, const int b,
                                     const void* __restrict__ tgt,
                                     const void* __restrict__ hist,
                                     const int* __restrict__ mask,
                                     const void* __restrict__ Wq,
                                     const void* __restrict__ Wk,
                                     const void* __restrict__ Wv,
                                     const void* __restrict__ Wo,
                                     void* __restrict__ out) {
  const float NINF = -__builtin_inff();
  const size_t esz = F32 ? 4 : 2;
  float* tvec = ws.u;        // [128]
  float* qv   = ws.u + DD;   // [128]

  // P0: target row -> f32 LDS (2 elems/lane)
  if constexpr (F32) {
    *(float2*)&tvec[2 * lane] = ((const float2*)tgt)[(size_t)b * 64 + lane];
  } else {
    const unsigned int dw = ((const unsigned int*)tgt)[(size_t)b * 64 + lane];
    *(float2*)&tvec[2 * lane] = make_float2(blo(dw), bhi(dw));
  }
  __syncthreads();

  // P1: q[i] = Wq[i,:] . t   (2 rows/lane)
#pragma unroll
  for (int r = 0; r < 2; r++) {
    const int i = lane + 64 * r;
    qv[i] = rowdot128<F32>((const char*)Wq + (size_t)i * DD * esz, tvec);
  }
  __syncthreads();

  // P2: qt[j*4+h] = RSCALE * sum_d q[h*32+d] * Wk[h*32+d][j]
#pragma unroll
  for (int h = 0; h < NH; h++) {
#pragma unroll
    for (int r = 0; r < 2; r++) {
      const int j = lane + 64 * r;
      float acc = 0.f;
#pragma unroll
      for (int d = 0; d < 32; d++)
        acc += qv[h * 32 + d] * welem<F32>(Wk, (size_t)(h * 32 + d) * DD + j);
      ws.qt[j * NH + h] = acc * RSCALE;
    }
  }
  __syncthreads();

  // Phase B: scores for rows l = lane+64k (k=0..2) and 192+(lane&7) (lane<8 owns it).
  // Hist loads predicated on mask -> masked rows never fetched.
  int lrow[4];
  int am[4];
#pragma unroll
  for (int k = 0; k < 3; k++) lrow[k] = lane + 64 * k;
  lrow[3] = 192 + (lane & 7);
#pragma unroll
  for (int k = 0; k < 4; k++) am[k] = mask[(size_t)b * LL + lrow[k]] != 0;
  if (lane >= 8) am[3] = 0;

  float acc[4][4];
#pragma unroll
  for (int k = 0; k < 4; k++)
#pragma unroll
    for (int h = 0; h < 4; h++) acc[k][h] = 0.f;

  const float4* qt4 = (const float4*)ws.qt;

  if constexpr (!F32) {
    const unsigned int* hb =
        (const unsigned int*)((const unsigned short*)hist + (size_t)b * LL * DD);
    uint4 rb[4][2] = {};
#pragma unroll 2
    for (int c = 0; c < 8; c++) {           // 8 chunks x 16 columns
#pragma unroll
      for (int k = 0; k < 4; k++)
        if (am[k]) {
          const uint4* p = (const uint4*)&hb[lrow[k] * 64 + (c << 3)];
          rb[k][0] = p[0];
          rb[k][1] = p[1];
        }
#pragma unroll
      for (int d2 = 0; d2 < 8; d2++) {      // dword within chunk (2 columns)
        const int jj = (c << 4) + (d2 << 1);
        const float4 q0 = qt4[jj];          // lane-uniform LDS -> broadcast
        const float4 q1 = qt4[jj + 1];
#pragma unroll
        for (int k = 0; k < 4; k++) {
          const uint4 v = rb[k][d2 >> 2];
          const unsigned int dw = ((d2 & 3) == 0) ? v.x
                                : ((d2 & 3) == 1) ? v.y
                                : ((d2 & 3) == 2) ? v.z : v.w;
          const float f0 = blo(dw), f1 = bhi(dw);
          acc[k][0] += f0 * q0.x + f1 * q1.x;
          acc[k][1] += f0 * q0.y + f1 * q1.y;
          acc[k][2] += f0 * q0.z + f1 * q1.z;
          acc[k][3] += f0 * q0.w + f1 * q1.w;
        }
      }
    }
  } else {
    const float* hf = (const float*)hist + (size_t)b * LL * DD;
    float4 rb[4] = {};
#pragma unroll 4
    for (int c = 0; c < 32; c++) {          // 32 chunks x 4 columns
#pragma unroll
      for (int k = 0; k < 4; k++)
        if (am[k]) rb[k] = *(const float4*)&hf[(size_t)lrow[k] * DD + (c << 2)];
      const float4 q0 = qt4[(c << 2)];
      const float4 q1 = qt4[(c << 2) + 1];
      const float4 q2 = qt4[(c << 2) + 2];
      const float4 q3 = qt4[(c << 2) + 3];
#pragma unroll
      for (int k = 0; k < 4; k++) {
        acc[k][0] += rb[k].x * q0.x + rb[k].y * q1.x + rb[k].z * q2.x + rb[k].w * q3.x;
        acc[k][1] += rb[k].x * q0.y + rb[k].y * q1.y + rb[k].z * q2.y + rb[k].w * q3.y;
        acc[k][2] += rb[k].x * q0.z + rb[k].y * q1.z + rb[k].z * q2.z + rb[k].w * q3.z;
        acc[k][3] += rb[k].x * q0.w + rb[k].y * q1.w + rb[k].z * q2.w + rb[k].w * q3.w;
      }
    }
  }

  // mask -> scores (kills garbage from predicated-off loads)
#pragma unroll
  for (int k = 0; k < 4; k++)
#pragma unroll
    for (int h = 0; h < 4; h++) acc[k][h] = am[k] ? acc[k][h] : NINF;

  // Softmax per head, wave-wide shuffle reductions (all rows live in this wave)
  float rr[4];
#pragma unroll
  for (int h = 0; h < 4; h++) {
    float m = fmaxf(fmaxf(acc[0][h], acc[1][h]), fmaxf(acc[2][h], acc[3][h]));
#pragma unroll
    for (int off = 32; off; off >>= 1) m = fmaxf(m, __shfl_xor(m, off));
    float e0 = __expf(acc[0][h] - m);
    float e1 = __expf(acc[1][h] - m);
    float e2 = __expf(acc[2][h] - m);
    float e3 = __expf(acc[3][h] - m);
    acc[0][h] = e0; acc[1][h] = e1; acc[2][h] = e2; acc[3][h] = e3;
    float su = e0 + e1 + e2 + e3;
#pragma unroll
    for (int off = 32; off; off >>= 1) su += __shfl_xor(su, off);
    rr[h] = 1.f / su;
  }

  // Compaction: keep only active rows (attn != 0) -> phase D runs ~cnt (~100) iters
  int* sidx = (int*)ws.u;   // overlays tvec/qv (both dead)
  const unsigned long long lt = (1ull << lane) - 1ull;
  int base = 0;
#pragma unroll
  for (int k = 0; k < 4; k++) {
    const unsigned long long bal = __ballot(am[k] != 0);
    const int pos = base + (int)__popcll(bal & lt);
    if (am[k]) {
      sidx[pos] = lrow[k];
      *(float4*)&ws.sc[pos * 4] = make_float4(acc[k][0] * rr[0], acc[k][1] * rr[1],
                                              acc[k][2] * rr[2], acc[k][3] * rr[3]);
    }
    base += (int)__popcll(bal);
  }
  const int cnt = base;
  __syncthreads();

  // Phase D: c[h][j] over compacted rows; lane = column pair
  float4 cl = make_float4(0.f, 0.f, 0.f, 0.f);   // heads x low col
  float4 chh = make_float4(0.f, 0.f, 0.f, 0.f);  // heads x high col
  const int j2 = lane;
  if constexpr (!F32) {
    const unsigned int* hd =
        (const unsigned int*)((const unsigned short*)hist + (size_t)b * LL * DD) + j2;
    int i = 0;
    for (; i + 4 <= cnt; i += 4) {
      const int4 li = *(const int4*)&sidx[i];
      const unsigned int w0 = hd[li.x << 6];
      const unsigned int w1 = hd[li.y << 6];
      const unsigned int w2 = hd[li.z << 6];
      const unsigned int w3 = hd[li.w << 6];
      const float4 a0 = *(const float4*)&ws.sc[(i + 0) * 4];
      const float4 a1 = *(const float4*)&ws.sc[(i + 1) * 4];
      const float4 a2 = *(const float4*)&ws.sc[(i + 2) * 4];
      const float4 a3 = *(const float4*)&ws.sc[(i + 3) * 4];
      float f0, f1;
      f0 = blo(w0); f1 = bhi(w0);
      cl.x += f0 * a0.x; cl.y += f0 * a0.y; cl.z += f0 * a0.z; cl.w += f0 * a0.w;
      chh.x += f1 * a0.x; chh.y += f1 * a0.y; chh.z += f1 * a0.z; chh.w += f1 * a0.w;
      f0 = blo(w1); f1 = bhi(w1);
      cl.x += f0 * a1.x; cl.y += f0 * a1.y; cl.z += f0 * a1.z; cl.w += f0 * a1.w;
      chh.x += f1 * a1.x; chh.y += f1 * a1.y; chh.z += f1 * a1.z; chh.w += f1 * a1.w;
      f0 = blo(w2); f1 = bhi(w2);
      cl.x += f0 * a2.x; cl.y += f0 * a2.y; cl.z += f0 * a2.z; cl.w += f0 * a2.w;
      chh.x += f1 * a2.x; chh.y += f1 * a2.y; chh.z += f1 * a2.z; chh.w += f1 * a2.w;
      f0 = blo(w3); f1 = bhi(w3);
      cl.x += f0 * a3.x; cl.y += f0 * a3.y; cl.z += f0 * a3.z; cl.w += f0 * a3.w;
      chh.x += f1 * a3.x; chh.y += f1 * a3.y; chh.z += f1 * a3.z; chh.w += f1 * a3.w;
    }
    for (; i < cnt; i++) {
      const int l = sidx[i];
      const unsigned int w0 = hd[l << 6];
      const float4 a0 = *(const float4*)&ws.sc[i * 4];
      const float f0 = blo(w0), f1 = bhi(w0);
      cl.x += f0 * a0.x; cl.y += f0 * a0.y; cl.z += f0 * a0.z; cl.w += f0 * a0.w;
      chh.x += f1 * a0.x; chh.y += f1 * a0.y; chh.z += f1 * a0.z; chh.w += f1 * a0.w;
    }
  } else {
    const float2* hf = (const float2*)((const float*)hist + (size_t)b * LL * DD) + j2;
    int i = 0;
    for (; i + 4 <= cnt; i += 4) {
      const int4 li = *(const int4*)&sidx[i];
      const float2 w0 = hf[li.x << 6];
      const float2 w1 = hf[li.y << 6];
      const float2 w2 = hf[li.z << 6];
      const float2 w3 = hf[li.w << 6];
      const float4 a0 = *(const float4*)&ws.sc[(i + 0) * 4];
      const float4 a1 = *(const float4*)&ws.sc[(i + 1) * 4];
      const float4 a2 = *(const float4*)&ws.sc[(i + 2) * 4];
      const float4 a3 = *(const float4*)&ws.sc[(i + 3) * 4];
      cl.x += w0.x * a0.x; cl.y += w0.x * a0.y; cl.z += w0.x * a0.z; cl.w += w0.x * a0.w;
      chh.x += w0.y * a0.x; chh.y += w0.y * a0.y; chh.z += w0.y * a0.z; chh.w += w0.y * a0.w;
      cl.x += w1.x * a1.x; cl.y += w1.x * a1.y; cl.z += w1.x * a1.z; cl.w += w1.x * a1.w;
      chh.x += w1.y * a1.x; chh.y += w1.y * a1.y; chh.z += w1.y * a1.z; chh.w += w1.y * a1.w;
      cl.x += w2.x * a2.x; cl.y += w2.x * a2.y; cl.z += w2.x * a2.z; cl.w += w2.x * a2.w;
      chh.x += w2.y * a2.x; chh.y += w2.y * a2.y; chh.z += w2.y * a2.z; chh.w += w2.y * a2.w;
      cl.x += w3.x * a3.x; cl.y += w3.x * a3.y; cl.z += w3.x * a3.z; cl.w += w3.x * a3.w;
      chh.x += w3.y * a3.x; chh.y += w3.y * a3.y; chh.z += w3.y * a3.z; chh.w += w3.y * a3.w;
    }
    for (; i < cnt; i++) {
      const int l = sidx[i];
      const float2 w0 = hf[l << 6];
      const float4 a0 = *(const float4*)&ws.sc[i * 4];
      cl.x += w0.x * a0.x; cl.y += w0.x * a0.y; cl.z += w0.x * a0.z; cl.w += w0.x * a0.w;
      chh.x += w0.y * a0.x; chh.y += w0.y * a0.y; chh.z += w0.y * a0.z; chh.w += w0.y * a0.w;
    }
  }

  // cvec[h][j] (reuses qt)
  float* cvec = ws.qt;
  *(float2*)&cvec[0 * DD + 2 * j2] = make_float2(cl.x, chh.x);
  *(float2*)&cvec[1 * DD + 2 * j2] = make_float2(cl.y, chh.y);
  *(float2*)&cvec[2 * DD + 2 * j2] = make_float2(cl.z, chh.z);
  *(float2*)&cvec[3 * DD + 2 * j2] = make_float2(cl.w, chh.w);
  __syncthreads();

  // P7b: o[i] = Wv[i,:] . c[head(i)]  (ovec overlays sidx, dead now)
  float* ovec = ws.u;
#pragma unroll
  for (int r = 0; r < 2; r++) {
    const int i = lane + 64 * r;
    ovec[i] = rowdot128<F32>((const char*)Wv + (size_t)i * DD * esz,
                             &cvec[(i >> 5) * DD]);
  }
  __syncthreads();

  // P8: out[i'] = Wo[i',:] . o   (2 adjacent rows/lane -> packed store)
  {
    const int i0 = 2 * lane, i1 = 2 * lane + 1;
    const float o0 = rowdot128<F32>((const char*)Wo + (size_t)i0 * DD * esz, ovec);
    const float o1 = rowdot128<F32>((const char*)Wo + (size_t)i1 * DD * esz, ovec);
    if constexpr (F32) ((float2*)out)[(size_t)b * 64 + lane] = make_float2(o0, o1);
    else               ((unsigned int*)out)[(size_t)b * 64 + lane] = pack2(o0, o1);
  }
}

// Fused kernel: per-block dtype probe; wave w owns batch row b = blk*4 + w.
__global__ __launch_bounds__(256, 5)
void mhta_kernel(const void* __restrict__ tgt,   // [B,128]
                 const void* __restrict__ hist,  // [B,200,128]
                 const int* __restrict__ mask,   // [B,200] i32
                 const void* __restrict__ Wq,    // [128,128]
                 const void* __restrict__ Wk,
                 const void* __restrict__ Wv,
                 const void* __restrict__ Wo,
                 void* __restrict__ out,         // [B,128]
                 const int Btot)
{
  __shared__ WaveSmem sm[WPB];
  __shared__ int flag;
  const int tid = threadIdx.x;
  const int lane = tid & 63;
  const int wv = tid >> 6;
  int b = blockIdx.x * WPB + wv;
  if (b >= Btot) b = Btot - 1;

  if (tid < 64) {
    // bf16 data: low half of each dword is a bf16 normal (exp in [110,134]);
    // f32 data: those bits are mantissa bits (~10% in range)
    const unsigned int* hd = (const unsigned int*)hist;
    const unsigned int e = (hd[tid] >> 7) & 0xffu;
    const unsigned long long bal = __ballot(e >= 110u && e <= 134u);
    if (tid == 0) flag = (__popcll(bal) < 32) ? 1 : 0;
  }
  __syncthreads();

  if (flag) body<true >(sm[wv], lane, b, tgt, hist, mask, Wq, Wk, Wv, Wo, out);
  else      body<false>(sm[wv], lane, b, tgt, hist, mask, Wq, Wk, Wv, Wo, out);
}

extern "C" void kernel_launch(void* const* d_in, const int* in_sizes, int n_in,
                              void* d_out, int out_size, void* d_ws, size_t ws_size,
                              hipStream_t stream) {
  const void* tgt  = d_in[0];
  const void* hist = d_in[1];
  const int*  mask = (const int*)d_in[2];
  const void* Wq   = d_in[3];
  const void* Wk   = d_in[4];
  const void* Wv   = d_in[5];
  const void* Wo   = d_in[6];

  const int B = in_sizes[0] / DD;   // 4096
  const int nb = (B + WPB - 1) / WPB;

  mhta_kernel<<<dim3(nb), dim3(256), 0, stream>>>(tgt, hist, mask, Wq, Wk, Wv, Wo, d_out, B);
}